// Round 7
// baseline (135.523 us; speedup 1.0000x reference)
//
#include <hip/hip_runtime.h>
#include <hip/hip_bf16.h>
#include <math.h>

// PolicyHead, fused, producer/consumer pipelined:
//   kLN  = LayerNorm(key_table); bqk = kLN.bq
//   Wk   = Wq @ kLN^T (4096x128-pad f16) FRAGMENT-TILED (Bf), L2-resident
//   out[b] = log_softmax(mask(gather(backbone[b]@Wk + bqk)/16) + bias)
//
// gemm_fused_k (512 thr): waves 0-3 PRODUCERS stream A (f32, 1KB-contiguous
// per instr) -> reg ring (depth 2) -> f16 -> swizzled LDS, write-late; waves
// 4-7 CONSUMERS run MFMA from LDS + B-frags from L2. Rationale: vmcnt is
// per-wave FIFO; in R2-R6 every MFMA B-wait drained the A-prefetches (~300cyc
// max hiding). Specialized producer waves keep 16KB/wave in flight across a
// full iteration (~1500+cyc). Loop uses raw s_barrier + lgkmcnt(0) only --
// NO vmcnt(0) drain in the loop (no __syncthreads until epilogue).
//
// ws: [0,1MB) Bf f16 | [1MB,+83K) tableLN | [1MB+128K,+512B) bqk

typedef _Float16 half8_t __attribute__((ext_vector_type(8)));
typedef _Float16 half4_t __attribute__((ext_vector_type(4)));
typedef float    f32x4_t __attribute__((ext_vector_type(4)));

#define NUM_B 16384
#define D_IN  4096
#define D_Q   256
#define N_ACT 40

__device__ __forceinline__ half8_t cvt8(const float4 a, const float4 b) {
  half8_t h;
  h[0] = (_Float16)a.x; h[1] = (_Float16)a.y; h[2] = (_Float16)a.z; h[3] = (_Float16)a.w;
  h[4] = (_Float16)b.x; h[5] = (_Float16)b.y; h[6] = (_Float16)b.z; h[7] = (_Float16)b.w;
  return h;
}
__device__ __forceinline__ half4_t cvt4(const float4 a) {
  half4_t h;
  h[0] = (_Float16)a.x; h[1] = (_Float16)a.y; h[2] = (_Float16)a.z; h[3] = (_Float16)a.w;
  return h;
}
__device__ __forceinline__ void wait_lgkm0() {
  asm volatile("s_waitcnt lgkmcnt(0)" ::: "memory");
}
__device__ __forceinline__ void bar() {
  __builtin_amdgcn_s_barrier();
  __builtin_amdgcn_sched_barrier(0);
}

// ---------------------------------------------------------------------------
__global__ __launch_bounds__(256) void ln_table_k(const float* __restrict__ kt,
                                                  const float* __restrict__ gamma,
                                                  const float* __restrict__ beta,
                                                  const float* __restrict__ bq,
                                                  float* __restrict__ out,
                                                  float* __restrict__ bqk) {
  __shared__ float red[8];
  __shared__ float red2[4];
  const int t = threadIdx.x, r = blockIdx.x;
  float v = kt[r * 256 + t];
  float s = v, sq = v * v;
#pragma unroll
  for (int off = 1; off < 64; off <<= 1) {
    s  += __shfl_xor(s, off);
    sq += __shfl_xor(sq, off);
  }
  if ((t & 63) == 0) { red[t >> 6] = s; red[4 + (t >> 6)] = sq; }
  __syncthreads();
  s  = red[0] + red[1] + red[2] + red[3];
  sq = red[4] + red[5] + red[6] + red[7];
  const float mu  = s * (1.0f / 256.0f);
  const float var = sq * (1.0f / 256.0f) - mu * mu;
  const float inv = 1.0f / sqrtf(var + 1e-5f);
  const float o = (v - mu) * inv * gamma[t] + beta[t];
  out[r * 256 + t] = o;
  float p = o * bq[t];
#pragma unroll
  for (int off = 1; off < 64; off <<= 1) p += __shfl_xor(p, off);
  if ((t & 63) == 0) red2[t >> 6] = p;
  __syncthreads();
  if (t == 0) bqk[r] = red2[0] + red2[1] + red2[2] + red2[3];
}

// ---------------------------------------------------------------------------
// Wk = Wq(4096x256) @ kLN^T(256x81->128 zero-pad), f16, fragment-tiled:
// element (k,n) -> halves idx ((k>>5)*8+(n>>4))*512 + (((k>>3)&3)*16+(n&15))*8 + (k&7)
__global__ __launch_bounds__(256) void wk_gemm_k(const float* __restrict__ Wq,
                                                 const float* __restrict__ tbl,
                                                 _Float16* __restrict__ Bf) {
  const int lane = threadIdx.x & 63, w = threadIdx.x >> 6;
  const int wm = w >> 1, wn = w & 1;
  const int m0 = blockIdx.x * 64 + wm * 32;
  const int n0 = wn * 64;
  const int fr = lane & 15, fg = lane >> 4;
  f32x4_t acc[2][4] = {};
  for (int k0 = 0; k0 < 256; k0 += 32) {
    half8_t af[2], bf[4];
#pragma unroll
    for (int i = 0; i < 2; ++i) {
      const float* p = Wq + (size_t)(m0 + i * 16 + fr) * D_Q + k0 + fg * 8;
      af[i] = cvt8(*(const float4*)p, *(const float4*)(p + 4));
    }
#pragma unroll
    for (int j = 0; j < 4; ++j) {
      const int n = n0 + j * 16 + fr;
      if (n < 81) {
        const float* p = tbl + (size_t)n * D_Q + k0 + fg * 8;
        bf[j] = cvt8(*(const float4*)p, *(const float4*)(p + 4));
      } else {
        bf[j] = (half8_t)(_Float16)0.0f;
      }
    }
#pragma unroll
    for (int i = 0; i < 2; ++i)
#pragma unroll
      for (int j = 0; j < 4; ++j)
        acc[i][j] = __builtin_amdgcn_mfma_f32_16x16x32_f16(af[i], bf[j], acc[i][j], 0, 0, 0);
  }
#pragma unroll
  for (int i = 0; i < 2; ++i)
#pragma unroll
    for (int j = 0; j < 4; ++j)
#pragma unroll
      for (int r = 0; r < 4; ++r) {
        const int k = m0 + i * 16 + fg * 4 + r;
        const int n = n0 + j * 16 + fr;
        const int kt32 = k >> 5, fgb = (k >> 3) & 3, e = k & 7;
        const int jg = n >> 4, frb = n & 15;
        Bf[(((size_t)kt32 * 8 + jg) * 64 + fgb * 16 + frb) * 8 + e] =
            (_Float16)acc[i][j][r];
      }
}

// ---------------------------------------------------------------------------
// Producer macros: issue tile T into reg array dst; write reg array src
// (tile kt+1) into LDS buffer buf. Static reg indexing via unroll-2 parity.
#define PISSUE(dst, T)                                                        \
  do {                                                                        \
    _Pragma("unroll") for (int s_ = 0; s_ < 8; ++s_)                          \
        dst[s_] = *(const float4*)(ap0 + (size_t)s_ * D_IN + (size_t)(T) * 256); \
  } while (0)
#define PWRITE(src, buf)                                                      \
  do {                                                                        \
    _Pragma("unroll") for (int s_ = 0; s_ < 8; ++s_)                          \
        *(half4_t*)&Al[buf][awo[s_]] = cvt4(src[s_]);                         \
  } while (0)

__global__ __launch_bounds__(512) void gemm_fused_k(const float* __restrict__ A,
                                                    const _Float16* __restrict__ Bf,
                                                    const float* __restrict__ bqk,
                                                    const int* __restrict__ va,
                                                    const int* __restrict__ phase,
                                                    const int* __restrict__ trick,
                                                    const float* __restrict__ psig,
                                                    float* __restrict__ out) {
  __shared__ _Float16 Al[2][32 * 256];  // 2 x 16KB; epilogue reuses as f32 C
  const int t = threadIdx.x, lane = t & 63, w = t >> 6;
  const int fr = lane & 15, fg = lane >> 4;
  const size_t row0 = (size_t)blockIdx.x * 32;

  if (w < 4) {
    // ---------------- producers: waves 0-3, rows w*8 .. w*8+7 ----------------
    const float* ap0 = A + (row0 + w * 8) * (size_t)D_IN + lane * 4;
    int awo[8];
#pragma unroll
    for (int s = 0; s < 8; ++s) {
      const int rr = w * 8 + s;  // rr&7 == s
      awo[s] = rr * 256 + (((lane >> 1) ^ s) * 8) + (lane & 1) * 4;
    }
    float4 ra[8], rb[8];
    PISSUE(ra, 0);
    PISSUE(rb, 1);
    PWRITE(ra, 0);  // compiler emits vmcnt(8): waits T0, keeps T1 in flight
    wait_lgkm0();
    bar();
#pragma unroll 2
    for (int kt = 0; kt < 16; ++kt) {
      if ((kt & 1) == 0) {
        if (kt + 2 < 16) PISSUE(ra, kt + 2);   // ra free: T(kt) written last iter
        PWRITE(rb, 1);                         // T(kt+1) -> Al[1]; vmcnt(8)
      } else {
        if (kt + 2 < 16) PISSUE(rb, kt + 2);
        if (kt + 1 < 16) PWRITE(ra, 0);        // T(kt+1) -> Al[0]
      }
      wait_lgkm0();
      bar();
    }
  } else {
    // ---------------- consumers: waves 4-7, tile 16x64 each ------------------
    const int cw = w - 4, wm = cw >> 1, wn = cw & 1;
    int aoff[8];
#pragma unroll
    for (int kk = 0; kk < 8; ++kk)
      aoff[kk] = (wm * 16 + fr) * 256 + (((kk * 4 + fg) ^ (fr & 7)) * 8);
    const _Float16* bb = Bf + (size_t)lane * 8;

    f32x4_t acc[4] = {};
    wait_lgkm0();
    bar();
    for (int kt = 0; kt < 16; ++kt) {
      const _Float16* albase = &Al[kt & 1][0];
#pragma unroll
      for (int kk = 0; kk < 8; ++kk) {
        const half8_t af = *(const half8_t*)(albase + aoff[kk]);
        half8_t bf[4];
#pragma unroll
        for (int j = 0; j < 4; ++j)
          bf[j] = *(const half8_t*)(bb + (((size_t)(kt * 8 + kk) * 8 + wn * 4 + j) * 512));
#pragma unroll
        for (int j = 0; j < 4; ++j)
          acc[j] = __builtin_amdgcn_mfma_f32_16x16x32_f16(af, bf[j], acc[j], 0, 0, 0);
      }
      wait_lgkm0();
      bar();
    }
    // C -> LDS (f32, stride 132): row = wm*16+fg*4+r, col = wn*64+j*16+fr
    float* C = (float*)&Al[0][0];  // 32*132*4 = 16.9KB < 32KB
#pragma unroll
    for (int j = 0; j < 4; ++j) {
      const int col = wn * 64 + j * 16 + fr;
#pragma unroll
      for (int r = 0; r < 4; ++r)
        C[(wm * 16 + fg * 4 + r) * 132 + col] = acc[j][r];
    }
  }

  __syncthreads();  // full drain OK here (once)

  // ---- gather + bias + log_softmax: 8 waves x 4 rows each
  const float* C = (const float*)&Al[0][0];
  for (int rr = 0; rr < 4; ++rr) {
    const int row = w * 4 + rr;
    const size_t b = row0 + row;
    int rank = -1, suit = 0;
    if (lane < N_ACT) {
      rank = va[(b * N_ACT + lane) * 2];
      suit = va[(b * N_ACT + lane) * 2 + 1];
    }
    const int ph = phase[b];
    const bool valid = (rank >= 0);
    const int aidx = valid ? (suit == 4 ? 80 : ph * 40 + suit * 9 + rank) : -1;
    const int nvalid = __popcll(__ballot(valid));

    float logit = -INFINITY;
    if (valid) logit = (C[row * 132 + aidx] + bqk[aidx]) * 0.0625f;  // /sqrt(256)

    if (ph == 1 && lane == 0) {
      const float ps = psig[trick[b]];
      const float nv = (float)nvalid;
      const float wv = (nv == 1.0f) ? 0.0f
                                    : logf(fmaxf((1.0f - ps) / ps * (nv - 1.0f), 1e-5f));
      logit += wv;
    }

    float m = logit;
#pragma unroll
    for (int off = 1; off < 64; off <<= 1) m = fmaxf(m, __shfl_xor(m, off));
    const float e = expf(logit - m);
    float ssum = e;
#pragma unroll
    for (int off = 1; off < 64; off <<= 1) ssum += __shfl_xor(ssum, off);
    const float o = logit - m - logf(ssum);
    // finite sentinel at masked positions (ref has -inf; (-inf)-(-inf)=NaN)
    if (lane < N_ACT) out[b * N_ACT + lane] = valid ? o : -3.0e38f;
  }
}

// ---------------------------------------------------------------------------
extern "C" void kernel_launch(void* const* d_in, const int* in_sizes, int n_in,
                              void* d_out, int out_size, void* d_ws, size_t ws_size,
                              hipStream_t stream) {
  const float* backbone = (const float*)d_in[0];
  const int*   va       = (const int*)d_in[1];
  const int*   phase    = (const int*)d_in[2];
  const int*   trick    = (const int*)d_in[3];
  const float* Wq       = (const float*)d_in[4];
  const float* bq       = (const float*)d_in[5];
  const float* keytab   = (const float*)d_in[6];
  const float* gamma    = (const float*)d_in[7];
  const float* beta     = (const float*)d_in[8];
  const float* psig     = (const float*)d_in[9];
  float* out = (float*)d_out;

  char* ws = (char*)d_ws;
  _Float16* Bf   = (_Float16*)ws;                             // 1 MB
  float* tableLN = (float*)(ws + (1u << 20));                 // 83 KB
  float* bqk     = (float*)(ws + (1u << 20) + (128u << 10));  // 324 B

  ln_table_k<<<dim3(81), 256, 0, stream>>>(keytab, gamma, beta, bq, tableLN, bqk);
  wk_gemm_k<<<dim3(64), 256, 0, stream>>>(Wq, tableLN, Bf);
  gemm_fused_k<<<dim3(NUM_B / 32), 512, 0, stream>>>(backbone, Bf, bqk, va,
                                                     phase, trick, psig, out);
}

// Round 8
// 100.647 us; speedup vs baseline: 1.3465x; 1.3465x over previous
//
#include <hip/hip_runtime.h>
#include <hip/hip_bf16.h>
#include <math.h>

// PolicyHead, fused, all-LDS-staged + counted-vmcnt pipeline:
//   kLN = LayerNorm(key_table); bqk = kLN.bq
//   Wk  = Wq @ kLN^T (4096x128-pad f16) FRAGMENT-TILED (Bf)
//   out[b] = log_softmax(mask(gather(backbone[b]@Wk + bqk)/16) + bias)
//
// R7 post-mortem: B-frag re-reads from L2/L3 were 1 GB/dispatch (4x the A
// stream) -- THE bottleneck all along. Fix: stage B into LDS once per block
// iteration (Bf tiling => linear LDS dest, direct global_load_lds), and
// stage A as f32 via global_load_lds too (cvt at frag-read). Per wave per
// iter: exactly 3 global_load_lds; pipeline with s_waitcnt vmcnt(3) (never
// vmcnt(0) in-loop) + raw s_barrier. BM=32, BK=64, 64 iters, LDS 48KB,
// 512 blocks (2/CU). B-traffic: 512MB -> L2-resident per XCD.
//
// ws: [0,1MB) Bf f16 | [1MB,+83K) tableLN | [1MB+128K,+512B) bqk

typedef _Float16 half8_t __attribute__((ext_vector_type(8)));
typedef float    f32x4_t __attribute__((ext_vector_type(4)));

#define NUM_B 16384
#define D_IN  4096
#define D_Q   256
#define N_ACT 40

__device__ __forceinline__ half8_t cvt8(const float4 a, const float4 b) {
  half8_t h;
  h[0] = (_Float16)a.x; h[1] = (_Float16)a.y; h[2] = (_Float16)a.z; h[3] = (_Float16)a.w;
  h[4] = (_Float16)b.x; h[5] = (_Float16)b.y; h[6] = (_Float16)b.z; h[7] = (_Float16)b.w;
  return h;
}
__device__ __forceinline__ void gl_lds16f(const float* g, float* l) {
  __builtin_amdgcn_global_load_lds(
      (const __attribute__((address_space(1))) void*)g,
      (__attribute__((address_space(3))) void*)l, 16, 0, 0);
}
__device__ __forceinline__ void gl_lds16h(const _Float16* g, _Float16* l) {
  __builtin_amdgcn_global_load_lds(
      (const __attribute__((address_space(1))) void*)g,
      (__attribute__((address_space(3))) void*)l, 16, 0, 0);
}

// ---------------------------------------------------------------------------
__global__ __launch_bounds__(256) void ln_table_k(const float* __restrict__ kt,
                                                  const float* __restrict__ gamma,
                                                  const float* __restrict__ beta,
                                                  const float* __restrict__ bq,
                                                  float* __restrict__ out,
                                                  float* __restrict__ bqk) {
  __shared__ float red[8];
  __shared__ float red2[4];
  const int t = threadIdx.x, r = blockIdx.x;
  float v = kt[r * 256 + t];
  float s = v, sq = v * v;
#pragma unroll
  for (int off = 1; off < 64; off <<= 1) {
    s  += __shfl_xor(s, off);
    sq += __shfl_xor(sq, off);
  }
  if ((t & 63) == 0) { red[t >> 6] = s; red[4 + (t >> 6)] = sq; }
  __syncthreads();
  s  = red[0] + red[1] + red[2] + red[3];
  sq = red[4] + red[5] + red[6] + red[7];
  const float mu  = s * (1.0f / 256.0f);
  const float var = sq * (1.0f / 256.0f) - mu * mu;
  const float inv = 1.0f / sqrtf(var + 1e-5f);
  const float o = (v - mu) * inv * gamma[t] + beta[t];
  out[r * 256 + t] = o;
  float p = o * bq[t];
#pragma unroll
  for (int off = 1; off < 64; off <<= 1) p += __shfl_xor(p, off);
  if ((t & 63) == 0) red2[t >> 6] = p;
  __syncthreads();
  if (t == 0) bqk[r] = red2[0] + red2[1] + red2[2] + red2[3];
}

// ---------------------------------------------------------------------------
// Wk = Wq(4096x256) @ kLN^T(256x81->128 zero-pad), f16, fragment-tiled:
// element (k,n) -> halves idx ((k>>5)*8+(n>>4))*512 + (((k>>3)&3)*16+(n&15))*8 + (k&7)
__global__ __launch_bounds__(256) void wk_gemm_k(const float* __restrict__ Wq,
                                                 const float* __restrict__ tbl,
                                                 _Float16* __restrict__ Bf) {
  const int lane = threadIdx.x & 63, w = threadIdx.x >> 6;
  const int wm = w >> 1, wn = w & 1;
  const int m0 = blockIdx.x * 64 + wm * 32;
  const int n0 = wn * 64;
  const int fr = lane & 15, fg = lane >> 4;
  f32x4_t acc[2][4] = {};
  for (int k0 = 0; k0 < 256; k0 += 32) {
    half8_t af[2], bf[4];
#pragma unroll
    for (int i = 0; i < 2; ++i) {
      const float* p = Wq + (size_t)(m0 + i * 16 + fr) * D_Q + k0 + fg * 8;
      af[i] = cvt8(*(const float4*)p, *(const float4*)(p + 4));
    }
#pragma unroll
    for (int j = 0; j < 4; ++j) {
      const int n = n0 + j * 16 + fr;
      if (n < 81) {
        const float* p = tbl + (size_t)n * D_Q + k0 + fg * 8;
        bf[j] = cvt8(*(const float4*)p, *(const float4*)(p + 4));
      } else {
        bf[j] = (half8_t)(_Float16)0.0f;
      }
    }
#pragma unroll
    for (int i = 0; i < 2; ++i)
#pragma unroll
      for (int j = 0; j < 4; ++j)
        acc[i][j] = __builtin_amdgcn_mfma_f32_16x16x32_f16(af[i], bf[j], acc[i][j], 0, 0, 0);
  }
#pragma unroll
  for (int i = 0; i < 2; ++i)
#pragma unroll
    for (int j = 0; j < 4; ++j)
#pragma unroll
      for (int r = 0; r < 4; ++r) {
        const int k = m0 + i * 16 + fg * 4 + r;
        const int n = n0 + j * 16 + fr;
        const int kt32 = k >> 5, fgb = (k >> 3) & 3, e = k & 7;
        const int jg = n >> 4, frb = n & 15;
        Bf[(((size_t)kt32 * 8 + jg) * 64 + fgb * 16 + frb) * 8 + e] =
            (_Float16)acc[i][j][r];
      }
}

// ---------------------------------------------------------------------------
// Fused GEMM + gather + bias + log_softmax.
// Block: 512 thr / 8 waves, 32 batch rows x 128 cols, K=4096, BK=64 (64 it).
// LDS: Af[2][32][64] f32 (2x8KB, A source-swizzled unit^=(row&7)),
//      Bl[2][8192] f16 (2x16KB, linear copy of Bf 16KB chunk). Total 48KB.
// Staging: 24 global_load_lds per iter (8 A + 16 B), 3 per wave; pipeline
// with s_waitcnt vmcnt(3) + s_barrier; lgkmcnt(0)+s_barrier after compute.
__global__ __launch_bounds__(512) void gemm_fused_k(const float* __restrict__ A,
                                                    const _Float16* __restrict__ Bf,
                                                    const float* __restrict__ bqk,
                                                    const int* __restrict__ va,
                                                    const int* __restrict__ phase,
                                                    const int* __restrict__ trick,
                                                    const float* __restrict__ psig,
                                                    float* __restrict__ out) {
  __shared__ __align__(16) char smem[49152];
  float*    Afs = (float*)smem;                 // [2][2048] f32
  _Float16* Bls = (_Float16*)(smem + 16384);    // [2][8192] f16

  const int t = threadIdx.x, lane = t & 63, w = t >> 6;
  const int fr = lane & 15, fg = lane >> 4;
  const size_t row0 = (size_t)blockIdx.x * 32;

  // ---- staging: unified instr list, id = w*3+q (0..23). id<8: A, else B.
#define STAGE(T, P)                                                            \
  do {                                                                         \
    float* abase = Afs + (P)*2048;                                             \
    _Float16* bbase = Bls + (P)*8192;                                          \
    _Pragma("unroll") for (int q_ = 0; q_ < 3; ++q_) {                         \
      const int id_ = w * 3 + q_;                                              \
      if (id_ < 8) {                                                           \
        const int r_ = id_ * 4 + (lane >> 4);                                  \
        gl_lds16f(A + (size_t)(row0 + r_) * D_IN + (T)*64 +                    \
                      (((lane & 15) ^ (r_ & 7)) << 2),                         \
                  abase + id_ * 256);                                          \
      } else {                                                                 \
        const int ib_ = id_ - 8;                                               \
        gl_lds16h(Bf + (size_t)(T)*8192 + ib_ * 512 + lane * 8,                \
                  bbase + ib_ * 512);                                          \
      }                                                                        \
    }                                                                          \
  } while (0)

  // ---- frag read offsets
  const int wm = w >> 2, wn = w & 3;  // wave tile: rows wm*16..+16, cols wn*32..+32
  int aoff[2][2], boff[2][2];
#pragma unroll
  for (int c = 0; c < 2; ++c) {
#pragma unroll
    for (int h = 0; h < 2; ++h)
      aoff[c][h] = (wm * 16 + fr) * 64 + (c * 8 + ((fg * 2 + h) ^ (fr & 7))) * 4;
#pragma unroll
    for (int j = 0; j < 2; ++j)
      boff[c][j] = c * 4096 + (wn * 2 + j) * 512 + lane * 8;
  }

  f32x4_t acc[2] = {};

  STAGE(0, 0);
  for (int kt = 0; kt < 64; ++kt) {
    if (kt < 63) STAGE(kt + 1, (kt + 1) & 1);
    __builtin_amdgcn_sched_barrier(0);
    if (kt < 63) asm volatile("s_waitcnt vmcnt(3)" ::: "memory");
    else         asm volatile("s_waitcnt vmcnt(0)" ::: "memory");
    __builtin_amdgcn_s_barrier();
    __builtin_amdgcn_sched_barrier(0);

    const float*    Ap = Afs + (kt & 1) * 2048;
    const _Float16* Bp = Bls + (kt & 1) * 8192;
#pragma unroll
    for (int c = 0; c < 2; ++c) {
      const float4 x0 = *(const float4*)(Ap + aoff[c][0]);
      const float4 x1 = *(const float4*)(Ap + aoff[c][1]);
      const half8_t af = cvt8(x0, x1);
#pragma unroll
      for (int j = 0; j < 2; ++j) {
        const half8_t bf = *(const half8_t*)(Bp + boff[c][j]);
        acc[j] = __builtin_amdgcn_mfma_f32_16x16x32_f16(af, bf, acc[j], 0, 0, 0);
      }
    }
    asm volatile("s_waitcnt lgkmcnt(0)" ::: "memory");
    __builtin_amdgcn_s_barrier();
    __builtin_amdgcn_sched_barrier(0);
  }
#undef STAGE

  // ---- epilogue: C (32x132 f32 = 16.9KB) overlays dead staging LDS
  __syncthreads();
  float* C = (float*)smem;
#pragma unroll
  for (int j = 0; j < 2; ++j) {
    const int col = (wn * 2 + j) * 16 + fr;
#pragma unroll
    for (int r = 0; r < 4; ++r)
      C[(wm * 16 + fg * 4 + r) * 132 + col] = acc[j][r];
  }
  __syncthreads();

  // gather + bias + log_softmax: 8 waves x 4 rows
  for (int rr = 0; rr < 4; ++rr) {
    const int row = w * 4 + rr;
    const size_t b = row0 + row;
    int rank = -1, suit = 0;
    if (lane < N_ACT) {
      rank = va[(b * N_ACT + lane) * 2];
      suit = va[(b * N_ACT + lane) * 2 + 1];
    }
    const int ph = phase[b];
    const bool valid = (rank >= 0);
    const int aidx = valid ? (suit == 4 ? 80 : ph * 40 + suit * 9 + rank) : -1;
    const int nvalid = __popcll(__ballot(valid));

    float logit = -INFINITY;
    if (valid) logit = (C[row * 132 + aidx] + bqk[aidx]) * 0.0625f;  // /sqrt(256)

    if (ph == 1 && lane == 0) {
      const float ps = psig[trick[b]];
      const float nv = (float)nvalid;
      const float wv = (nv == 1.0f) ? 0.0f
                                    : logf(fmaxf((1.0f - ps) / ps * (nv - 1.0f), 1e-5f));
      logit += wv;
    }

    float m = logit;
#pragma unroll
    for (int off = 1; off < 64; off <<= 1) m = fmaxf(m, __shfl_xor(m, off));
    const float e = expf(logit - m);
    float ssum = e;
#pragma unroll
    for (int off = 1; off < 64; off <<= 1) ssum += __shfl_xor(ssum, off);
    const float o = logit - m - logf(ssum);
    // finite sentinel at masked positions (ref has -inf; (-inf)-(-inf)=NaN)
    if (lane < N_ACT) out[b * N_ACT + lane] = valid ? o : -3.0e38f;
  }
}

// ---------------------------------------------------------------------------
extern "C" void kernel_launch(void* const* d_in, const int* in_sizes, int n_in,
                              void* d_out, int out_size, void* d_ws, size_t ws_size,
                              hipStream_t stream) {
  const float* backbone = (const float*)d_in[0];
  const int*   va       = (const int*)d_in[1];
  const int*   phase    = (const int*)d_in[2];
  const int*   trick    = (const int*)d_in[3];
  const float* Wq       = (const float*)d_in[4];
  const float* bq       = (const float*)d_in[5];
  const float* keytab   = (const float*)d_in[6];
  const float* gamma    = (const float*)d_in[7];
  const float* beta     = (const float*)d_in[8];
  const float* psig     = (const float*)d_in[9];
  float* out = (float*)d_out;

  char* ws = (char*)d_ws;
  _Float16* Bf   = (_Float16*)ws;                             // 1 MB
  float* tableLN = (float*)(ws + (1u << 20));                 // 83 KB
  float* bqk     = (float*)(ws + (1u << 20) + (128u << 10));  // 324 B

  ln_table_k<<<dim3(81), 256, 0, stream>>>(keytab, gamma, beta, bq, tableLN, bqk);
  wk_gemm_k<<<dim3(64), 256, 0, stream>>>(Wq, tableLN, Bf);
  gemm_fused_k<<<dim3(NUM_B / 32), 512, 0, stream>>>(backbone, Bf, bqk, va,
                                                     phase, trick, psig, out);
}